// Round 12
// baseline (630.017 us; speedup 1.0000x reference)
//
#include <hip/hip_runtime.h>
#include <hip/hip_bf16.h>

// Problem dims (fixed)
#define Nn   512
#define NN   262144        // N*N positions
#define EDG  16384

typedef unsigned short u16;
typedef short v8s __attribute__((ext_vector_type(8)));   // 8 bf16 lanes (4 VGPR)
typedef float v4f __attribute__((ext_vector_type(4)));
typedef u16 u16x8 __attribute__((ext_vector_type(8)));

__device__ __forceinline__ float b2f(u16 u) {
    union { unsigned int i; float f; } v; v.i = ((unsigned int)u) << 16; return v.f;
}
__device__ __forceinline__ u16 f2b(float f) {
    union { float f; unsigned int i; } v; v.f = f;
    unsigned int r = (v.i + 0x7FFFu + ((v.i >> 16) & 1u)) >> 16;
    return (u16)r;
}

// ---------------------------------------------------------------------------
__global__ void sentinel_kernel(float* __restrict__ out, float val) {
    if (threadIdx.x < 10) out[threadIdx.x] = val;
}

// ---------------------------------------------------------------------------
// K0: convert the 6 conv weight tensors (fp32) into one bf16 arena.
__global__ void cvt_weights(const float* __restrict__ s0, const float* __restrict__ s1,
                            const float* __restrict__ s2, const float* __restrict__ s3,
                            const float* __restrict__ s4, const float* __restrict__ s5,
                            u16* __restrict__ dst) {
    int t = blockIdx.x * 256 + threadIdx.x;
    if (t >= 43008) return;
    float v;
    if      (t < 2048)  v = s0[t];
    else if (t < 4096)  v = s1[t - 2048];
    else if (t < 10240) v = s2[t - 4096];
    else if (t < 18432) v = s3[t - 10240];
    else if (t < 26624) v = s4[t - 18432];
    else                v = s5[t - 26624];
    dst[t] = f2b(v);
}

// ---------------------------------------------------------------------------
// K1: scatter edges into A (fp32, pos-major [p][32]); x is fp32 [512][16]
__global__ void scatter_edges(const float* __restrict__ x, const int* __restrict__ ei,
                              float* __restrict__ A) {
    int t = blockIdx.x * 256 + threadIdx.x;
    if (t >= EDG * 32) return;
    int e = t >> 5, c = t & 31;
    int s = ei[e], d = ei[EDG + e];
    float v = (c < 16) ? x[s * 16 + c] : x[d * 16 + (c - 16)];
    atomicAdd(A + ((size_t)s * Nn + d) * 32 + c, v);
}

// ---------------------------------------------------------------------------
// K2: A fp32 pos-major [p][32] -> u0 CHANNEL-MAJOR bf16 [32][NN]; totals into tt0[64..]
__global__ __launch_bounds__(256) void finalize_u0(const float* __restrict__ A,
                                                   u16* __restrict__ u0,
                                                   float* __restrict__ total) {
    __shared__ u16 L[32 * 258];
    __shared__ float red[4][32];
    int t = threadIdx.x;
    int p0 = blockIdx.x * 256;
    const float* Ar = A + (size_t)(p0 + t) * 32;
    float v[32];
#pragma unroll
    for (int c = 0; c < 32; ++c) v[c] = Ar[c];
#pragma unroll
    for (int c = 0; c < 32; ++c) L[c * 258 + t] = f2b(v[c]);
    int wv = t >> 6;
#pragma unroll
    for (int c = 0; c < 32; ++c) {
        float r = v[c];
        for (int off = 32; off > 0; off >>= 1) r += __shfl_down(r, off);
        if ((t & 63) == 0) red[wv][c] = r;
    }
    __syncthreads();
    if (t < 32) atomicAdd(total + t, red[0][t] + red[1][t] + red[2][t] + red[3][t]);
    int off = (t & 31) * 8, rb = t >> 5;
#pragma unroll
    for (int pass = 0; pass < 4; ++pass) {
        int c = pass * 8 + rb;
        u16x8 w = *(const u16x8*)(L + c * 258 + off);
        *(u16x8*)(u0 + (size_t)c * NN + p0 + off) = w;
    }
}

// ---------------------------------------------------------------------------
// K3: trace of channel-major activation; grid = C blocks.
__global__ void trace_raw_cm(const u16* __restrict__ ucm, float* __restrict__ trraw) {
    int c = blockIdx.x, t = threadIdx.x;
    const u16* base = ucm + (size_t)c * NN;
    float s = b2f(base[(size_t)(2 * t) * 513]) + b2f(base[(size_t)(2 * t + 1) * 513]);
    for (int off = 32; off > 0; off >>= 1) s += __shfl_down(s, off);
    __shared__ float r[4];
    if ((t & 63) == 0) r[t >> 6] = s;
    __syncthreads();
    if (t == 0) trraw[c] = r[0] + r[1] + r[2] + r[3];
}

// ---------------------------------------------------------------------------
// K5: merged conv1+conv2 (r9, proven). Block = 128 positions.
template<int NCH>
__global__ __launch_bounds__(256) void conv12_t(
    const u16* __restrict__ src,
    const float* __restrict__ sc, const float* __restrict__ sh,
    const u16* __restrict__ w1, const float* __restrict__ b1,
    const u16* __restrict__ w2, const float* __restrict__ b2,
    u16* __restrict__ dst1, u16* __restrict__ dst2)
{
    __shared__ u16 LS[8320];
    const int C = NCH * 32;
    const int t = threadIdx.x;
    const int P0 = blockIdx.x * 128;
    const int lane = t & 63, wave = t >> 6;
    const int l15 = lane & 15, quad = lane >> 4;
    const int pw = wave * 32;
    const int sr = t >> 4;
    const int so = (t & 15) * 8;

    u16x8 pf[NCH][2];
#pragma unroll
    for (int kc = 0; kc < NCH; ++kc)
#pragma unroll
        for (int ps = 0; ps < 2; ++ps)
            pf[kc][ps] = *(const u16x8*)(src + (size_t)(kc * 32 + ps * 16 + sr) * NN + P0 + so);

    v4f acc[2][4][2];
#pragma unroll
    for (int s = 0; s < 2; ++s)
#pragma unroll
        for (int mt = 0; mt < 4; ++mt)
#pragma unroll
            for (int nt = 0; nt < 2; ++nt) acc[s][mt][nt] = (v4f){0.f, 0.f, 0.f, 0.f};

    {
        u16* Ln = LS;
#pragma unroll
        for (int ps = 0; ps < 2; ++ps) {
            int c = ps * 16 + sr;
            u16x8 v = pf[0][ps];
            if (sc) {
                float s = sc[c], f = sh[c];
#pragma unroll
                for (int j = 0; j < 8; ++j) v[j] = f2b(b2f(v[j]) * s + f);
            }
            *(u16x8*)(Ln + c * 130 + so) = v;
        }
    }
    __syncthreads();
#pragma unroll
    for (int kc = 0; kc < NCH; ++kc) {
        if (kc + 1 < NCH) {
            u16* Ln = LS + ((kc + 1) & 1) * 4160;
#pragma unroll
            for (int ps = 0; ps < 2; ++ps) {
                int c = ps * 16 + sr;
                int cg = (kc + 1) * 32 + c;
                u16x8 v = pf[kc + 1][ps];
                if (sc) {
                    float s = sc[cg], f = sh[cg];
#pragma unroll
                    for (int j = 0; j < 8; ++j) v[j] = f2b(b2f(v[j]) * s + f);
                }
                *(u16x8*)(Ln + c * 130 + so) = v;
            }
        }
        v8s af1[4], af2[4];
#pragma unroll
        for (int mt = 0; mt < 4; ++mt) {
            af1[mt] = *(const v8s*)(w1 + (mt * 16 + l15) * C + kc * 32 + quad * 8);
            af2[mt] = *(const v8s*)(w2 + (mt * 16 + l15) * C + kc * 32 + quad * 8);
        }
        const u16* Lb = LS + (kc & 1) * 4160;
#pragma unroll
        for (int nt = 0; nt < 2; ++nt) {
            const int p = pw + nt * 16 + l15;
            v8s b;
#pragma unroll
            for (int j = 0; j < 8; ++j) b[j] = (short)Lb[(quad * 8 + j) * 130 + p];
#pragma unroll
            for (int mt = 0; mt < 4; ++mt) {
                acc[0][mt][nt] = __builtin_amdgcn_mfma_f32_16x16x32_bf16(af1[mt], b, acc[0][mt][nt], 0, 0, 0);
                acc[1][mt][nt] = __builtin_amdgcn_mfma_f32_16x16x32_bf16(af2[mt], b, acc[1][mt][nt], 0, 0, 0);
            }
        }
        if (kc + 1 < NCH) __syncthreads();
    }
#pragma unroll
    for (int s = 0; s < 2; ++s) {
        __syncthreads();
        const float* bb = s ? b2 : b1;
#pragma unroll
        for (int mt = 0; mt < 4; ++mt)
#pragma unroll
            for (int r = 0; r < 4; ++r) {
                const int h = mt * 16 + quad * 4 + r;
                const float bv = bb[h];
#pragma unroll
                for (int nt = 0; nt < 2; ++nt)
                    LS[h * 130 + pw + nt * 16 + l15] = f2b(acc[s][mt][nt][r] + bv);
            }
        __syncthreads();
        u16* dd = s ? dst2 : dst1;
#pragma unroll
        for (int ps = 0; ps < 4; ++ps) {
            int h = ps * 16 + sr;
            u16x8 v = *(const u16x8*)(LS + h * 130 + so);
            __builtin_nontemporal_store(v, (u16x8*)(dd + (size_t)h * NN + P0 + so));
        }
    }
}

// ---------------------------------------------------------------------------
// K6: m4 conv (r9, proven): per-block BN stat/trace partials, no atomics.
template<int NCH>
__global__ __launch_bounds__(256) void conv4_t(
    const u16* __restrict__ mult, const u16* __restrict__ u,
    const float* __restrict__ sc, const float* __restrict__ sh,
    const u16* __restrict__ w, const float* __restrict__ bias,
    u16* __restrict__ dst,
    float* __restrict__ psum, float* __restrict__ psq, float* __restrict__ ptr)
{
    __shared__ u16 LS[8320];
    __shared__ float R1[64][4], R2[64][4];
    const int K = NCH * 32;
    const int t = threadIdx.x;
    const int P0 = blockIdx.x * 128;
    const int lane = t & 63, wave = t >> 6;
    const int l15 = lane & 15, quad = lane >> 4;
    const int pw = wave * 32;
    const int sr = t >> 4;
    const int so = (t & 15) * 8;

    u16x8 pf[NCH][2];
#pragma unroll
    for (int kc = 0; kc < NCH; ++kc)
#pragma unroll
        for (int ps = 0; ps < 2; ++ps) {
            int cg = kc * 32 + ps * 16 + sr;
            const u16* gp = (cg < 64) ? (mult + (size_t)cg * NN + P0 + so)
                                      : (u + (size_t)(cg - 64) * NN + P0 + so);
            pf[kc][ps] = *(const u16x8*)gp;
        }

    v4f acc[4][2];
#pragma unroll
    for (int mt = 0; mt < 4; ++mt)
#pragma unroll
        for (int nt = 0; nt < 2; ++nt) acc[mt][nt] = (v4f){0.f, 0.f, 0.f, 0.f};

#pragma unroll
    for (int ps = 0; ps < 2; ++ps)
        *(u16x8*)(LS + (ps * 16 + sr) * 130 + so) = pf[0][ps];
    __syncthreads();
#pragma unroll
    for (int kc = 0; kc < NCH; ++kc) {
        if (kc + 1 < NCH) {
            u16* Ln = LS + ((kc + 1) & 1) * 4160;
#pragma unroll
            for (int ps = 0; ps < 2; ++ps) {
                int c = ps * 16 + sr;
                int cg = (kc + 1) * 32 + c;
                u16x8 v = pf[kc + 1][ps];
                if (cg >= 64 && sc) {
                    float s = sc[cg - 64], f = sh[cg - 64];
#pragma unroll
                    for (int j = 0; j < 8; ++j) v[j] = f2b(b2f(v[j]) * s + f);
                }
                *(u16x8*)(Ln + c * 130 + so) = v;
            }
        }
        v8s af[4];
#pragma unroll
        for (int mt = 0; mt < 4; ++mt)
            af[mt] = *(const v8s*)(w + (mt * 16 + l15) * K + kc * 32 + quad * 8);
        const u16* Lb = LS + (kc & 1) * 4160;
#pragma unroll
        for (int nt = 0; nt < 2; ++nt) {
            const int p = pw + nt * 16 + l15;
            v8s b;
#pragma unroll
            for (int j = 0; j < 8; ++j) b[j] = (short)Lb[(quad * 8 + j) * 130 + p];
#pragma unroll
            for (int mt = 0; mt < 4; ++mt)
                acc[mt][nt] = __builtin_amdgcn_mfma_f32_16x16x32_bf16(af[mt], b, acc[mt][nt], 0, 0, 0);
        }
        if (kc + 1 < NCH) __syncthreads();
    }
    __syncthreads();
#pragma unroll
    for (int mt = 0; mt < 4; ++mt)
#pragma unroll
        for (int r = 0; r < 4; ++r) {
            const int h = mt * 16 + quad * 4 + r;
            const float bv = bias[h];
#pragma unroll
            for (int nt = 0; nt < 2; ++nt)
                LS[h * 130 + pw + nt * 16 + l15] = f2b(acc[mt][nt][r] + bv);
        }
    __syncthreads();
    {
        int c = t >> 2, q = t & 3;
        const u16* row = LS + c * 130 + q * 32;
        float s = 0.f, s2 = 0.f;
#pragma unroll
        for (int i = 0; i < 32; ++i) { float v = b2f(row[i]); s += v; s2 += v * v; }
        R1[c][q] = s; R2[c][q] = s2;
    }
    __syncthreads();
    {
        int i = P0 >> 9, j0 = P0 & 511;
        int blk = blockIdx.x;
        if (t < 64) {
            psum[t * 2048 + blk] = R1[t][0] + R1[t][1] + R1[t][2] + R1[t][3];
            psq[t * 2048 + blk]  = R2[t][0] + R2[t][1] + R2[t][2] + R2[t][3];
            if (j0 <= i && i < j0 + 128) ptr[t * 512 + i] = b2f(LS[t * 130 + (i - j0)]);
        }
    }
#pragma unroll
    for (int ps = 0; ps < 4; ++ps) {
        int h = ps * 16 + sr;
        u16x8 v = *(const u16x8*)(LS + h * 130 + so);
        __builtin_nontemporal_store(v, (u16x8*)(dst + (size_t)h * NN + P0 + so));
    }
}

// ---------------------------------------------------------------------------
// K7 v5: batched per-channel GEMM. A-frags DIRECT FROM GLOBAL (L1-resident:
// all 4 waves share A); LB double-buffered -> ONE barrier per ck.
// ty from low blockIdx bits so blocks b,b+8 (same XCD round-robin) share A strip.
__global__ __launch_bounds__(256) void bmm_mfma(const u16* __restrict__ Aall,
                                                const u16* __restrict__ Ball,
                                                u16* __restrict__ Call) {
    __shared__ u16 LB[2][64 * 130];
    const int h = blockIdx.y;
    const int ty = blockIdx.x & 3, tx = blockIdx.x >> 2;
    const int t = threadIdx.x;
    const int lane = t & 63, wave = t >> 6;
    const int l15 = lane & 15, quad = lane >> 4;
    const int jb = wave * 32;
    const u16* Ap = Aall + (size_t)h * NN + (size_t)(ty * 128) * 512;
    const u16* Bp = Ball + (size_t)h * NN + tx * 128;
    const int bkr = t >> 4;           // 0..15
    const int bjg = (t & 15) * 8;

    v4f acc[8][2];
#pragma unroll
    for (int mt = 0; mt < 8; ++mt)
#pragma unroll
        for (int nt = 0; nt < 2; ++nt) acc[mt][nt] = (v4f){0.f, 0.f, 0.f, 0.f};

    v8s rb[4];
#pragma unroll
    for (int i = 0; i < 4; ++i)
        rb[i] = *(const v8s*)(Bp + (size_t)(i * 16 + bkr) * 512 + bjg);
#pragma unroll
    for (int i = 0; i < 4; ++i)
        *(v8s*)(&LB[0][(i * 16 + bkr) * 130 + bjg]) = rb[i];
    __syncthreads();

    for (int ck = 0; ck < 8; ++ck) {
        if (ck < 7) {
            const int k0 = (ck + 1) * 64;
#pragma unroll
            for (int i = 0; i < 4; ++i)
                rb[i] = *(const v8s*)(Bp + (size_t)(k0 + i * 16 + bkr) * 512 + bjg);
        }
        const u16* Lb = &LB[ck & 1][0];
        const u16* Akp = Ap + ck * 64 + quad * 8;
#pragma unroll
        for (int kk = 0; kk < 2; ++kk) {
            v8s b[2];
#pragma unroll
            for (int nt = 0; nt < 2; ++nt) {
                const int j = jb + nt * 16 + l15;
#pragma unroll
                for (int jj = 0; jj < 8; ++jj)
                    b[nt][jj] = (short)Lb[(kk * 32 + quad * 8 + jj) * 130 + j];
            }
#pragma unroll
            for (int mh = 0; mh < 2; ++mh) {
                v8s a[4];
#pragma unroll
                for (int m = 0; m < 4; ++m)
                    a[m] = *(const v8s*)(Akp + (size_t)(mh * 64 + m * 16 + l15) * 512 + kk * 32);
#pragma unroll
                for (int m = 0; m < 4; ++m)
#pragma unroll
                    for (int nt = 0; nt < 2; ++nt)
                        acc[mh * 4 + m][nt] = __builtin_amdgcn_mfma_f32_16x16x32_bf16(a[m], b[nt], acc[mh * 4 + m][nt], 0, 0, 0);
            }
        }
        if (ck < 7) {
            u16* Ln = &LB[(ck + 1) & 1][0];
#pragma unroll
            for (int i = 0; i < 4; ++i)
                *(v8s*)(Ln + (i * 16 + bkr) * 130 + bjg) = rb[i];
        }
        __syncthreads();
    }

    u16* Cp = Call + (size_t)h * NN;
#pragma unroll
    for (int mt = 0; mt < 8; ++mt)
#pragma unroll
        for (int r = 0; r < 4; ++r) {
            const int i = ty * 128 + mt * 16 + quad * 4 + r;
#pragma unroll
            for (int nt = 0; nt < 2; ++nt) {
                const int j = tx * 128 + jb + nt * 16 + l15;
                Cp[i * 512 + j] = f2b(acc[mt][nt][r]);
            }
        }
}

// ---------------------------------------------------------------------------
// K11: reduce per-block partials; BN scale/shift; normalized totals & trace.
__global__ __launch_bounds__(256) void bn_finalize(
    const float* __restrict__ psum, const float* __restrict__ psq,
    const float* __restrict__ ptr,
    const float* __restrict__ g, const float* __restrict__ b,
    float* __restrict__ scale, float* __restrict__ shift,
    float* __restrict__ ttl) {
    int c = blockIdx.x, t = threadIdx.x;
    float s = 0.f, q = 0.f, tr = 0.f;
    for (int k = t; k < 2048; k += 256) { s += psum[c * 2048 + k]; q += psq[c * 2048 + k]; }
    for (int k = t; k < 512; k += 256) tr += ptr[c * 512 + k];
    for (int off = 32; off > 0; off >>= 1) {
        s += __shfl_down(s, off); q += __shfl_down(q, off); tr += __shfl_down(tr, off);
    }
    __shared__ float r1[4], r2[4], r3[4];
    if ((t & 63) == 0) { r1[t >> 6] = s; r2[t >> 6] = q; r3[t >> 6] = tr; }
    __syncthreads();
    if (t == 0) {
        s = r1[0] + r1[1] + r1[2] + r1[3];
        q = r2[0] + r2[1] + r2[2] + r2[3];
        tr = r3[0] + r3[1] + r3[2] + r3[3];
        float mean = s * (1.f / 262144.f);
        float var = q * (1.f / 262144.f) - mean * mean;
        float sc = g[c] * rsqrtf(fmaxf(var, 0.f) + 1e-5f);
        float sh = b[c] - mean * sc;
        scale[c] = sc;
        shift[c] = sh;
        ttl[64 + c] = sc * s + 262144.f * sh;   // total
        ttl[c]      = sc * tr + 512.f * sh;     // trace
    }
}

// ---------------------------------------------------------------------------
// K12a: one extractor per block (4 blocks, 256 thr). thread=(h,q): q = c-quarter.
__global__ __launch_bounds__(256) void extractor_par(
    const float* __restrict__ tt,
    const float* __restrict__ np1w, const float* __restrict__ np1b,
    const float* __restrict__ np2w, const float* __restrict__ np3w,
    const float* __restrict__ fe1w, const float* __restrict__ fe1b,
    const float* __restrict__ fe2w, const float* __restrict__ fe3w,
    float* __restrict__ oacc_part) {
    __shared__ float red[64][4];
    __shared__ float xo[64];
    const int li = blockIdx.x;
    const int t = threadIdx.x;
    const int h = t >> 2, q = t & 3;
    const int C = (li == 0) ? 32 : 64;
    const float* w1 = (li == 0) ? np1w : fe1w + (li - 1) * 4096;
    const float* b1 = (li == 0) ? np1b : fe1b + (li - 1) * 64;
    const float* w2 = (li == 0) ? np2w : fe2w + (li - 1) * 4096;
    const float* w3 = (li == 0) ? np3w : fe3w + (li - 1) * 4096;
    const float* tr = tt + li * 128;
    const float* to = tr + 64;
    const int cpq = C >> 2;
    float p = 0.f;
    for (int i = 0; i < cpq; ++i) {
        int c = q * cpq + i;
        p += (tr[c] * (1.f / 512.f)) * w1[h * C + c]
           + ((to[c] - tr[c]) * (1.f / (512.f * 511.f))) * w2[h * C + c];
    }
    red[h][q] = p;
    __syncthreads();
    if (q == 0) xo[h] = b1[h] + red[h][0] + red[h][1] + red[h][2] + red[h][3];
    __syncthreads();
    float o = xo[h];
    float p3 = 0.f;
    for (int i = 0; i < 16; ++i) {
        int f = q * 16 + i;
        p3 += fmaxf(xo[f], 0.f) * w3[h * 64 + f];
    }
    __syncthreads();
    red[h][q] = p3;
    __syncthreads();
    if (q == 0) oacc_part[li * 64 + h] = o + red[h][0] + red[h][1] + red[h][2] + red[h][3];
}

// ---------------------------------------------------------------------------
// K12b: head, 256 threads, 4-way split per output.
__global__ __launch_bounds__(256) void head_par(
    const float* __restrict__ oacc_part,
    const float* __restrict__ acw, const float* __restrict__ acb,
    const float* __restrict__ flw, const float* __restrict__ flb,
    float* __restrict__ out) {
    __shared__ float x[64], x2[64], red[64][4], l[10];
    const int t = threadIdx.x;
    const int h = t >> 2, q = t & 3;
    if (q == 0) {
        float oa = oacc_part[h] + oacc_part[64 + h] + oacc_part[128 + h] + oacc_part[192 + h];
        x[h] = fmaxf(oa, 0.f) * (1.f / 3.f);
    }
    __syncthreads();
    float p = 0.f;
    for (int i = 0; i < 16; ++i) { int f = q * 16 + i; p += x[f] * acw[h * 64 + f]; }
    red[h][q] = p;
    __syncthreads();
    if (q == 0) {
        float y = acb[h] + red[h][0] + red[h][1] + red[h][2] + red[h][3];
        x2[h] = x[h] + fmaxf(y, 0.f);
    }
    __syncthreads();
    if (t < 40) {
        int hh = t >> 2, qq = t & 3;
        float p2 = 0.f;
        for (int i = 0; i < 16; ++i) { int f = qq * 16 + i; p2 += x2[f] * flw[hh * 64 + f]; }
        red[hh][qq] = p2;
    }
    __syncthreads();
    if (t < 10) l[t] = flb[t] + red[t][0] + red[t][1] + red[t][2] + red[t][3];
    __syncthreads();
    if (t == 0) {
        float m = l[0];
        for (int i = 1; i < 10; ++i) m = fmaxf(m, l[i]);
        float se = 0.f;
        for (int i = 0; i < 10; ++i) se += expf(l[i] - m);
        float ls = m + logf(se);
        for (int i = 0; i < 10; ++i) out[i] = l[i] - ls;
    }
}

// ---------------------------------------------------------------------------
extern "C" void kernel_launch(void* const* d_in, const int* in_sizes, int n_in,
                              void* d_out, int out_size, void* d_ws, size_t ws_size,
                              hipStream_t stream) {
    float* out = (float*)d_out;

    static const int exp_sizes[28] = {
        8192, 32768,
        2048, 64, 2048, 4096,
        2048, 64, 2048, 64, 6144, 64,
        8192, 128, 8192, 128, 16384, 128,
        192, 192,
        12288, 192, 12288, 12288,
        4096, 64, 640, 10
    };
    bool ok = (n_in == 28);
    if (ok) for (int i = 0; i < 28; ++i) if (in_sizes[i] != exp_sizes[i]) ok = false;
    if (!ok) { sentinel_kernel<<<1, 64, 0, stream>>>(out, -5.0f); return; }

    const size_t RSZ = (size_t)NN * 64 * 2;            // 33.55 MB per region
    const size_t BIG_OFF = 8192 + 90112;               // control (8KB) + bf16 weight arena
    if (ws_size < BIG_OFF + 4 * RSZ) {
        sentinel_kernel<<<1, 64, 0, stream>>>(out, -7.0f);
        return;
    }

    const float* x     = (const float*)d_in[0];
    const int*   ei    = (const int*)d_in[1];
    const float* np1w  = (const float*)d_in[2];
    const float* np1b  = (const float*)d_in[3];
    const float* np2w  = (const float*)d_in[4];
    const float* np3w  = (const float*)d_in[5];
    const float* c0m1b = (const float*)d_in[7];
    const float* c0m2b = (const float*)d_in[9];
    const float* c0m4b = (const float*)d_in[11];
    const float* cm1b  = (const float*)d_in[13];
    const float* cm2b  = (const float*)d_in[15];
    const float* cm4b  = (const float*)d_in[17];
    const float* bng   = (const float*)d_in[18];
    const float* bnb   = (const float*)d_in[19];
    const float* fe1w  = (const float*)d_in[20];
    const float* fe1b  = (const float*)d_in[21];
    const float* fe2w  = (const float*)d_in[22];
    const float* fe3w  = (const float*)d_in[23];
    const float* acw   = (const float*)d_in[24];
    const float* acb   = (const float*)d_in[25];
    const float* flw   = (const float*)d_in[26];
    const float* flb   = (const float*)d_in[27];

    char* ws = (char*)d_ws;
    float* small = (float*)ws;
    float* tt    = small;          // [4][128]: per-layer trace(64)|total(64)
    float* scl   = small + 512;
    float* shf   = small + 576;
    float* oaccp = small + 640;    // [4][64] extractor partials

    u16* arena = (u16*)(ws + 8192);          // bf16 conv weights, 43008 elements

    char* big = ws + BIG_OFF;
    u16* S0 = (u16*)(big + 0 * RSZ);
    u16* S1 = (u16*)(big + 1 * RSZ);
    u16* S2 = (u16*)(big + 2 * RSZ);
    u16* S3 = (u16*)(big + 3 * RSZ);
    float* Abuf = (float*)S2;                // fp32 staging, dead after finalize_u0

    // BN partial buffers live in S2 (o2 slot) — dead between bmm and next conv12.
    float* psum = (float*)S2;                          // 64*2048
    float* psq  = psum + 64 * 2048;                    // 64*2048
    float* ptr  = psq + 64 * 2048;                     // 64*512

    hipMemsetAsync(small, 0, 4096, stream);
    hipMemsetAsync(Abuf, 0, (size_t)NN * 32 * 4, stream);

    cvt_weights<<<168, 256, 0, stream>>>((const float*)d_in[6], (const float*)d_in[8],
                                         (const float*)d_in[10], (const float*)d_in[12],
                                         (const float*)d_in[14], (const float*)d_in[16], arena);
    scatter_edges<<<2048, 256, 0, stream>>>(x, ei, Abuf);
    finalize_u0<<<1024, 256, 0, stream>>>(Abuf, S0, tt + 64);        // total -> tt[0][64..]
    trace_raw_cm<<<32, 256, 0, stream>>>(S0, tt);                    // trace -> tt[0][0..31]

    u16* U[3]  = { S0, S1, S0 };
    u16* O1[3] = { S1, S0, S1 };
    u16* R[3]  = { S1, S0, S1 };

    const float *aff_s = nullptr, *aff_h = nullptr;

    for (int l = 0; l < 3; ++l) {
        int Cin = (l == 0) ? 32 : 64;
        const u16 *w1b, *w2b, *w4b;
        const float *b1, *b2, *b4;
        if (l == 0) {
            w1b = arena;            b1 = c0m1b;
            w2b = arena + 2048;     b2 = c0m2b;
            w4b = arena + 4096;     b4 = c0m4b;
        } else {
            int m = l - 1;
            w1b = arena + 10240 + m * 4096;  b1 = cm1b + m * 64;
            w2b = arena + 18432 + m * 4096;  b2 = cm2b + m * 64;
            w4b = arena + 26624 + m * 8192;  b4 = cm4b + m * 64;
        }
        if (Cin == 32)
            conv12_t<1><<<2048, 256, 0, stream>>>(U[l], aff_s, aff_h, w1b, b1, w2b, b2, O1[l], S2);
        else
            conv12_t<2><<<2048, 256, 0, stream>>>(U[l], aff_s, aff_h, w1b, b1, w2b, b2, O1[l], S2);
        bmm_mfma<<<dim3(16, 64), 256, 0, stream>>>(O1[l], S2, S3);
        if (Cin == 32)
            conv4_t<3><<<2048, 256, 0, stream>>>(S3, U[l], aff_s, aff_h, w4b, b4, R[l], psum, psq, ptr);
        else
            conv4_t<4><<<2048, 256, 0, stream>>>(S3, U[l], aff_s, aff_h, w4b, b4, R[l], psum, psq, ptr);
        bn_finalize<<<64, 256, 0, stream>>>(psum, psq, ptr, bng + l * 64, bnb + l * 64,
                                            scl, shf, tt + (l + 1) * 128);
        aff_s = scl; aff_h = shf;
    }
    extractor_par<<<4, 256, 0, stream>>>(tt, np1w, np1b, np2w, np3w,
                                         fe1w, fe1b, fe2w, fe3w, oaccp);
    head_par<<<1, 256, 0, stream>>>(oaccp, acw, acb, flw, flb, out);
}

// Round 13
// 575.047 us; speedup vs baseline: 1.0956x; 1.0956x over previous
//
#include <hip/hip_runtime.h>
#include <hip/hip_bf16.h>

// Problem dims (fixed)
#define Nn   512
#define NN   262144        // N*N positions
#define EDG  16384

typedef unsigned short u16;
typedef short v8s __attribute__((ext_vector_type(8)));   // 8 bf16 lanes (4 VGPR)
typedef float v4f __attribute__((ext_vector_type(4)));
typedef u16 u16x8 __attribute__((ext_vector_type(8)));

__device__ __forceinline__ float b2f(u16 u) {
    union { unsigned int i; float f; } v; v.i = ((unsigned int)u) << 16; return v.f;
}
__device__ __forceinline__ u16 f2b(float f) {
    union { float f; unsigned int i; } v; v.f = f;
    unsigned int r = (v.i + 0x7FFFu + ((v.i >> 16) & 1u)) >> 16;
    return (u16)r;
}

// ---------------------------------------------------------------------------
__global__ void sentinel_kernel(float* __restrict__ out, float val) {
    if (threadIdx.x < 10) out[threadIdx.x] = val;
}

// ---------------------------------------------------------------------------
// K0: convert the 6 conv weight tensors (fp32) into one bf16 arena.
__global__ void cvt_weights(const float* __restrict__ s0, const float* __restrict__ s1,
                            const float* __restrict__ s2, const float* __restrict__ s3,
                            const float* __restrict__ s4, const float* __restrict__ s5,
                            u16* __restrict__ dst) {
    int t = blockIdx.x * 256 + threadIdx.x;
    if (t >= 43008) return;
    float v;
    if      (t < 2048)  v = s0[t];
    else if (t < 4096)  v = s1[t - 2048];
    else if (t < 10240) v = s2[t - 4096];
    else if (t < 18432) v = s3[t - 10240];
    else if (t < 26624) v = s4[t - 18432];
    else                v = s5[t - 26624];
    dst[t] = f2b(v);
}

// ---------------------------------------------------------------------------
// K1: scatter edges into A (fp32, pos-major [p][32]); x is fp32 [512][16]
__global__ void scatter_edges(const float* __restrict__ x, const int* __restrict__ ei,
                              float* __restrict__ A) {
    int t = blockIdx.x * 256 + threadIdx.x;
    if (t >= EDG * 32) return;
    int e = t >> 5, c = t & 31;
    int s = ei[e], d = ei[EDG + e];
    float v = (c < 16) ? x[s * 16 + c] : x[d * 16 + (c - 16)];
    atomicAdd(A + ((size_t)s * Nn + d) * 32 + c, v);
}

// ---------------------------------------------------------------------------
// K2: A fp32 pos-major [p][32] -> u0 CHANNEL-MAJOR bf16 [32][NN]; totals into tt0[64..]
__global__ __launch_bounds__(256) void finalize_u0(const float* __restrict__ A,
                                                   u16* __restrict__ u0,
                                                   float* __restrict__ total) {
    __shared__ u16 L[32 * 258];
    __shared__ float red[4][32];
    int t = threadIdx.x;
    int p0 = blockIdx.x * 256;
    const float* Ar = A + (size_t)(p0 + t) * 32;
    float v[32];
#pragma unroll
    for (int c = 0; c < 32; ++c) v[c] = Ar[c];
#pragma unroll
    for (int c = 0; c < 32; ++c) L[c * 258 + t] = f2b(v[c]);
    int wv = t >> 6;
#pragma unroll
    for (int c = 0; c < 32; ++c) {
        float r = v[c];
        for (int off = 32; off > 0; off >>= 1) r += __shfl_down(r, off);
        if ((t & 63) == 0) red[wv][c] = r;
    }
    __syncthreads();
    if (t < 32) atomicAdd(total + t, red[0][t] + red[1][t] + red[2][t] + red[3][t]);
    int off = (t & 31) * 8, rb = t >> 5;
#pragma unroll
    for (int pass = 0; pass < 4; ++pass) {
        int c = pass * 8 + rb;
        u16x8 w = *(const u16x8*)(L + c * 258 + off);
        *(u16x8*)(u0 + (size_t)c * NN + p0 + off) = w;
    }
}

// ---------------------------------------------------------------------------
// K3: trace of channel-major activation; grid = C blocks.
__global__ void trace_raw_cm(const u16* __restrict__ ucm, float* __restrict__ trraw) {
    int c = blockIdx.x, t = threadIdx.x;
    const u16* base = ucm + (size_t)c * NN;
    float s = b2f(base[(size_t)(2 * t) * 513]) + b2f(base[(size_t)(2 * t + 1) * 513]);
    for (int off = 32; off > 0; off >>= 1) s += __shfl_down(s, off);
    __shared__ float r[4];
    if ((t & 63) == 0) r[t >> 6] = s;
    __syncthreads();
    if (t == 0) trraw[c] = r[0] + r[1] + r[2] + r[3];
}

// ---------------------------------------------------------------------------
// K5: merged conv1+conv2 (r9, proven). Block = 128 positions.
template<int NCH>
__global__ __launch_bounds__(256) void conv12_t(
    const u16* __restrict__ src,
    const float* __restrict__ sc, const float* __restrict__ sh,
    const u16* __restrict__ w1, const float* __restrict__ b1,
    const u16* __restrict__ w2, const float* __restrict__ b2,
    u16* __restrict__ dst1, u16* __restrict__ dst2)
{
    __shared__ u16 LS[8320];
    const int C = NCH * 32;
    const int t = threadIdx.x;
    const int P0 = blockIdx.x * 128;
    const int lane = t & 63, wave = t >> 6;
    const int l15 = lane & 15, quad = lane >> 4;
    const int pw = wave * 32;
    const int sr = t >> 4;
    const int so = (t & 15) * 8;

    u16x8 pf[NCH][2];
#pragma unroll
    for (int kc = 0; kc < NCH; ++kc)
#pragma unroll
        for (int ps = 0; ps < 2; ++ps)
            pf[kc][ps] = *(const u16x8*)(src + (size_t)(kc * 32 + ps * 16 + sr) * NN + P0 + so);

    v4f acc[2][4][2];
#pragma unroll
    for (int s = 0; s < 2; ++s)
#pragma unroll
        for (int mt = 0; mt < 4; ++mt)
#pragma unroll
            for (int nt = 0; nt < 2; ++nt) acc[s][mt][nt] = (v4f){0.f, 0.f, 0.f, 0.f};

    {
        u16* Ln = LS;
#pragma unroll
        for (int ps = 0; ps < 2; ++ps) {
            int c = ps * 16 + sr;
            u16x8 v = pf[0][ps];
            if (sc) {
                float s = sc[c], f = sh[c];
#pragma unroll
                for (int j = 0; j < 8; ++j) v[j] = f2b(b2f(v[j]) * s + f);
            }
            *(u16x8*)(Ln + c * 130 + so) = v;
        }
    }
    __syncthreads();
#pragma unroll
    for (int kc = 0; kc < NCH; ++kc) {
        if (kc + 1 < NCH) {
            u16* Ln = LS + ((kc + 1) & 1) * 4160;
#pragma unroll
            for (int ps = 0; ps < 2; ++ps) {
                int c = ps * 16 + sr;
                int cg = (kc + 1) * 32 + c;
                u16x8 v = pf[kc + 1][ps];
                if (sc) {
                    float s = sc[cg], f = sh[cg];
#pragma unroll
                    for (int j = 0; j < 8; ++j) v[j] = f2b(b2f(v[j]) * s + f);
                }
                *(u16x8*)(Ln + c * 130 + so) = v;
            }
        }
        v8s af1[4], af2[4];
#pragma unroll
        for (int mt = 0; mt < 4; ++mt) {
            af1[mt] = *(const v8s*)(w1 + (mt * 16 + l15) * C + kc * 32 + quad * 8);
            af2[mt] = *(const v8s*)(w2 + (mt * 16 + l15) * C + kc * 32 + quad * 8);
        }
        const u16* Lb = LS + (kc & 1) * 4160;
#pragma unroll
        for (int nt = 0; nt < 2; ++nt) {
            const int p = pw + nt * 16 + l15;
            v8s b;
#pragma unroll
            for (int j = 0; j < 8; ++j) b[j] = (short)Lb[(quad * 8 + j) * 130 + p];
#pragma unroll
            for (int mt = 0; mt < 4; ++mt) {
                acc[0][mt][nt] = __builtin_amdgcn_mfma_f32_16x16x32_bf16(af1[mt], b, acc[0][mt][nt], 0, 0, 0);
                acc[1][mt][nt] = __builtin_amdgcn_mfma_f32_16x16x32_bf16(af2[mt], b, acc[1][mt][nt], 0, 0, 0);
            }
        }
        if (kc + 1 < NCH) __syncthreads();
    }
#pragma unroll
    for (int s = 0; s < 2; ++s) {
        __syncthreads();
        const float* bb = s ? b2 : b1;
#pragma unroll
        for (int mt = 0; mt < 4; ++mt)
#pragma unroll
            for (int r = 0; r < 4; ++r) {
                const int h = mt * 16 + quad * 4 + r;
                const float bv = bb[h];
#pragma unroll
                for (int nt = 0; nt < 2; ++nt)
                    LS[h * 130 + pw + nt * 16 + l15] = f2b(acc[s][mt][nt][r] + bv);
            }
        __syncthreads();
        u16* dd = s ? dst2 : dst1;
#pragma unroll
        for (int ps = 0; ps < 4; ++ps) {
            int h = ps * 16 + sr;
            u16x8 v = *(const u16x8*)(LS + h * 130 + so);
            __builtin_nontemporal_store(v, (u16x8*)(dd + (size_t)h * NN + P0 + so));
        }
    }
}

// ---------------------------------------------------------------------------
// K6: m4 conv (r9, proven): per-block BN stat/trace partials, no atomics.
template<int NCH>
__global__ __launch_bounds__(256) void conv4_t(
    const u16* __restrict__ mult, const u16* __restrict__ u,
    const float* __restrict__ sc, const float* __restrict__ sh,
    const u16* __restrict__ w, const float* __restrict__ bias,
    u16* __restrict__ dst,
    float* __restrict__ psum, float* __restrict__ psq, float* __restrict__ ptr)
{
    __shared__ u16 LS[8320];
    __shared__ float R1[64][4], R2[64][4];
    const int K = NCH * 32;
    const int t = threadIdx.x;
    const int P0 = blockIdx.x * 128;
    const int lane = t & 63, wave = t >> 6;
    const int l15 = lane & 15, quad = lane >> 4;
    const int pw = wave * 32;
    const int sr = t >> 4;
    const int so = (t & 15) * 8;

    u16x8 pf[NCH][2];
#pragma unroll
    for (int kc = 0; kc < NCH; ++kc)
#pragma unroll
        for (int ps = 0; ps < 2; ++ps) {
            int cg = kc * 32 + ps * 16 + sr;
            const u16* gp = (cg < 64) ? (mult + (size_t)cg * NN + P0 + so)
                                      : (u + (size_t)(cg - 64) * NN + P0 + so);
            pf[kc][ps] = *(const u16x8*)gp;
        }

    v4f acc[4][2];
#pragma unroll
    for (int mt = 0; mt < 4; ++mt)
#pragma unroll
        for (int nt = 0; nt < 2; ++nt) acc[mt][nt] = (v4f){0.f, 0.f, 0.f, 0.f};

#pragma unroll
    for (int ps = 0; ps < 2; ++ps)
        *(u16x8*)(LS + (ps * 16 + sr) * 130 + so) = pf[0][ps];
    __syncthreads();
#pragma unroll
    for (int kc = 0; kc < NCH; ++kc) {
        if (kc + 1 < NCH) {
            u16* Ln = LS + ((kc + 1) & 1) * 4160;
#pragma unroll
            for (int ps = 0; ps < 2; ++ps) {
                int c = ps * 16 + sr;
                int cg = (kc + 1) * 32 + c;
                u16x8 v = pf[kc + 1][ps];
                if (cg >= 64 && sc) {
                    float s = sc[cg - 64], f = sh[cg - 64];
#pragma unroll
                    for (int j = 0; j < 8; ++j) v[j] = f2b(b2f(v[j]) * s + f);
                }
                *(u16x8*)(Ln + c * 130 + so) = v;
            }
        }
        v8s af[4];
#pragma unroll
        for (int mt = 0; mt < 4; ++mt)
            af[mt] = *(const v8s*)(w + (mt * 16 + l15) * K + kc * 32 + quad * 8);
        const u16* Lb = LS + (kc & 1) * 4160;
#pragma unroll
        for (int nt = 0; nt < 2; ++nt) {
            const int p = pw + nt * 16 + l15;
            v8s b;
#pragma unroll
            for (int j = 0; j < 8; ++j) b[j] = (short)Lb[(quad * 8 + j) * 130 + p];
#pragma unroll
            for (int mt = 0; mt < 4; ++mt)
                acc[mt][nt] = __builtin_amdgcn_mfma_f32_16x16x32_bf16(af[mt], b, acc[mt][nt], 0, 0, 0);
        }
        if (kc + 1 < NCH) __syncthreads();
    }
    __syncthreads();
#pragma unroll
    for (int mt = 0; mt < 4; ++mt)
#pragma unroll
        for (int r = 0; r < 4; ++r) {
            const int h = mt * 16 + quad * 4 + r;
            const float bv = bias[h];
#pragma unroll
            for (int nt = 0; nt < 2; ++nt)
                LS[h * 130 + pw + nt * 16 + l15] = f2b(acc[mt][nt][r] + bv);
        }
    __syncthreads();
    {
        int c = t >> 2, q = t & 3;
        const u16* row = LS + c * 130 + q * 32;
        float s = 0.f, s2 = 0.f;
#pragma unroll
        for (int i = 0; i < 32; ++i) { float v = b2f(row[i]); s += v; s2 += v * v; }
        R1[c][q] = s; R2[c][q] = s2;
    }
    __syncthreads();
    {
        int i = P0 >> 9, j0 = P0 & 511;
        int blk = blockIdx.x;
        if (t < 64) {
            psum[t * 2048 + blk] = R1[t][0] + R1[t][1] + R1[t][2] + R1[t][3];
            psq[t * 2048 + blk]  = R2[t][0] + R2[t][1] + R2[t][2] + R2[t][3];
            if (j0 <= i && i < j0 + 128) ptr[t * 512 + i] = b2f(LS[t * 130 + (i - j0)]);
        }
    }
#pragma unroll
    for (int ps = 0; ps < 4; ++ps) {
        int h = ps * 16 + sr;
        u16x8 v = *(const u16x8*)(LS + h * 130 + so);
        __builtin_nontemporal_store(v, (u16x8*)(dst + (size_t)h * NN + P0 + so));
    }
}

// ---------------------------------------------------------------------------
// K7 v6: batched per-channel GEMM. A-frags from global WITH register prefetch
// across ck (fixes v5's latency stall); LB double-buffered -> one barrier/ck.
__global__ __launch_bounds__(256) void bmm_mfma(const u16* __restrict__ Aall,
                                                const u16* __restrict__ Ball,
                                                u16* __restrict__ Call) {
    __shared__ u16 LB[2][64 * 130];
    const int h = blockIdx.y;
    const int tx = blockIdx.x & 3, ty = blockIdx.x >> 2;
    const int t = threadIdx.x;
    const int lane = t & 63, wave = t >> 6;
    const int l15 = lane & 15, quad = lane >> 4;
    const int jb = wave * 32;
    const u16* Ap = Aall + (size_t)h * NN + (size_t)(ty * 128) * 512;
    const u16* Bp = Ball + (size_t)h * NN + tx * 128;
    const int bkr = t >> 4;           // 0..15
    const int bjg = (t & 15) * 8;
    // per-lane A base: row = mh*64 + m*16 + l15, col = ck*64 + kk*32 + quad*8
    const u16* Al = Ap + (size_t)l15 * 512 + quad * 8;

    v4f acc[8][2];
#pragma unroll
    for (int mt = 0; mt < 8; ++mt)
#pragma unroll
        for (int nt = 0; nt < 2; ++nt) acc[mt][nt] = (v4f){0.f, 0.f, 0.f, 0.f};

    v8s rb[4];
    v8s pa[2][8];   // [kk][mh*4+m] prefetched A frags for current ck
#pragma unroll
    for (int i = 0; i < 4; ++i)
        rb[i] = *(const v8s*)(Bp + (size_t)(i * 16 + bkr) * 512 + bjg);
#pragma unroll
    for (int kk = 0; kk < 2; ++kk)
#pragma unroll
        for (int mm = 0; mm < 8; ++mm)
            pa[kk][mm] = *(const v8s*)(Al + (size_t)(mm * 16) * 512 + kk * 32);
#pragma unroll
    for (int i = 0; i < 4; ++i)
        *(v8s*)(&LB[0][(i * 16 + bkr) * 130 + bjg]) = rb[i];
    __syncthreads();

#pragma unroll
    for (int ck = 0; ck < 8; ++ck) {
        if (ck < 7) {
            const int k0 = (ck + 1) * 64;
#pragma unroll
            for (int i = 0; i < 4; ++i)
                rb[i] = *(const v8s*)(Bp + (size_t)(k0 + i * 16 + bkr) * 512 + bjg);
        }
        const u16* Lb = &LB[ck & 1][0];
#pragma unroll
        for (int kk = 0; kk < 2; ++kk) {
            v8s b[2];
#pragma unroll
            for (int nt = 0; nt < 2; ++nt) {
                const int j = jb + nt * 16 + l15;
#pragma unroll
                for (int jj = 0; jj < 8; ++jj)
                    b[nt][jj] = (short)Lb[(kk * 32 + quad * 8 + jj) * 130 + j];
            }
#pragma unroll
            for (int mm = 0; mm < 8; ++mm)
#pragma unroll
                for (int nt = 0; nt < 2; ++nt)
                    acc[mm][nt] = __builtin_amdgcn_mfma_f32_16x16x32_bf16(pa[kk][mm], b[nt], acc[mm][nt], 0, 0, 0);
            if (ck < 7) {   // prefetch next ck's A frags for this kk (regs now free)
                const int koff = (ck + 1) * 64 + kk * 32;
#pragma unroll
                for (int mm = 0; mm < 8; ++mm)
                    pa[kk][mm] = *(const v8s*)(Al + (size_t)(mm * 16) * 512 + koff);
            }
        }
        if (ck < 7) {
            u16* Ln = &LB[(ck + 1) & 1][0];
#pragma unroll
            for (int i = 0; i < 4; ++i)
                *(v8s*)(Ln + (i * 16 + bkr) * 130 + bjg) = rb[i];
        }
        __syncthreads();
    }

    u16* Cp = Call + (size_t)h * NN;
#pragma unroll
    for (int mt = 0; mt < 8; ++mt)
#pragma unroll
        for (int r = 0; r < 4; ++r) {
            const int i = ty * 128 + mt * 16 + quad * 4 + r;
#pragma unroll
            for (int nt = 0; nt < 2; ++nt) {
                const int j = tx * 128 + jb + nt * 16 + l15;
                Cp[i * 512 + j] = f2b(acc[mt][nt][r]);
            }
        }
}

// ---------------------------------------------------------------------------
// K11: reduce per-block partials; BN scale/shift; normalized totals & trace.
__global__ __launch_bounds__(256) void bn_finalize(
    const float* __restrict__ psum, const float* __restrict__ psq,
    const float* __restrict__ ptr,
    const float* __restrict__ g, const float* __restrict__ b,
    float* __restrict__ scale, float* __restrict__ shift,
    float* __restrict__ ttl) {
    int c = blockIdx.x, t = threadIdx.x;
    float s = 0.f, q = 0.f, tr = 0.f;
    for (int k = t; k < 2048; k += 256) { s += psum[c * 2048 + k]; q += psq[c * 2048 + k]; }
    for (int k = t; k < 512; k += 256) tr += ptr[c * 512 + k];
    for (int off = 32; off > 0; off >>= 1) {
        s += __shfl_down(s, off); q += __shfl_down(q, off); tr += __shfl_down(tr, off);
    }
    __shared__ float r1[4], r2[4], r3[4];
    if ((t & 63) == 0) { r1[t >> 6] = s; r2[t >> 6] = q; r3[t >> 6] = tr; }
    __syncthreads();
    if (t == 0) {
        s = r1[0] + r1[1] + r1[2] + r1[3];
        q = r2[0] + r2[1] + r2[2] + r2[3];
        tr = r3[0] + r3[1] + r3[2] + r3[3];
        float mean = s * (1.f / 262144.f);
        float var = q * (1.f / 262144.f) - mean * mean;
        float sc = g[c] * rsqrtf(fmaxf(var, 0.f) + 1e-5f);
        float sh = b[c] - mean * sc;
        scale[c] = sc;
        shift[c] = sh;
        ttl[64 + c] = sc * s + 262144.f * sh;   // total
        ttl[c]      = sc * tr + 512.f * sh;     // trace
    }
}

// ---------------------------------------------------------------------------
// K12a: one extractor per block (4 blocks, 256 thr). thread=(h,q): q = c-quarter.
__global__ __launch_bounds__(256) void extractor_par(
    const float* __restrict__ tt,
    const float* __restrict__ np1w, const float* __restrict__ np1b,
    const float* __restrict__ np2w, const float* __restrict__ np3w,
    const float* __restrict__ fe1w, const float* __restrict__ fe1b,
    const float* __restrict__ fe2w, const float* __restrict__ fe3w,
    float* __restrict__ oacc_part) {
    __shared__ float red[64][4];
    __shared__ float xo[64];
    const int li = blockIdx.x;
    const int t = threadIdx.x;
    const int h = t >> 2, q = t & 3;
    const int C = (li == 0) ? 32 : 64;
    const float* w1 = (li == 0) ? np1w : fe1w + (li - 1) * 4096;
    const float* b1 = (li == 0) ? np1b : fe1b + (li - 1) * 64;
    const float* w2 = (li == 0) ? np2w : fe2w + (li - 1) * 4096;
    const float* w3 = (li == 0) ? np3w : fe3w + (li - 1) * 4096;
    const float* tr = tt + li * 128;
    const float* to = tr + 64;
    const int cpq = C >> 2;
    float p = 0.f;
    for (int i = 0; i < cpq; ++i) {
        int c = q * cpq + i;
        p += (tr[c] * (1.f / 512.f)) * w1[h * C + c]
           + ((to[c] - tr[c]) * (1.f / (512.f * 511.f))) * w2[h * C + c];
    }
    red[h][q] = p;
    __syncthreads();
    if (q == 0) xo[h] = b1[h] + red[h][0] + red[h][1] + red[h][2] + red[h][3];
    __syncthreads();
    float o = xo[h];
    float p3 = 0.f;
    for (int i = 0; i < 16; ++i) {
        int f = q * 16 + i;
        p3 += fmaxf(xo[f], 0.f) * w3[h * 64 + f];
    }
    __syncthreads();
    red[h][q] = p3;
    __syncthreads();
    if (q == 0) oacc_part[li * 64 + h] = o + red[h][0] + red[h][1] + red[h][2] + red[h][3];
}

// ---------------------------------------------------------------------------
// K12b: head, 256 threads, 4-way split per output.
__global__ __launch_bounds__(256) void head_par(
    const float* __restrict__ oacc_part,
    const float* __restrict__ acw, const float* __restrict__ acb,
    const float* __restrict__ flw, const float* __restrict__ flb,
    float* __restrict__ out) {
    __shared__ float x[64], x2[64], red[64][4], l[10];
    const int t = threadIdx.x;
    const int h = t >> 2, q = t & 3;
    if (q == 0) {
        float oa = oacc_part[h] + oacc_part[64 + h] + oacc_part[128 + h] + oacc_part[192 + h];
        x[h] = fmaxf(oa, 0.f) * (1.f / 3.f);
    }
    __syncthreads();
    float p = 0.f;
    for (int i = 0; i < 16; ++i) { int f = q * 16 + i; p += x[f] * acw[h * 64 + f]; }
    red[h][q] = p;
    __syncthreads();
    if (q == 0) {
        float y = acb[h] + red[h][0] + red[h][1] + red[h][2] + red[h][3];
        x2[h] = x[h] + fmaxf(y, 0.f);
    }
    __syncthreads();
    if (t < 40) {
        int hh = t >> 2, qq = t & 3;
        float p2 = 0.f;
        for (int i = 0; i < 16; ++i) { int f = qq * 16 + i; p2 += x2[f] * flw[hh * 64 + f]; }
        red[hh][qq] = p2;
    }
    __syncthreads();
    if (t < 10) l[t] = flb[t] + red[t][0] + red[t][1] + red[t][2] + red[t][3];
    __syncthreads();
    if (t == 0) {
        float m = l[0];
        for (int i = 1; i < 10; ++i) m = fmaxf(m, l[i]);
        float se = 0.f;
        for (int i = 0; i < 10; ++i) se += expf(l[i] - m);
        float ls = m + logf(se);
        for (int i = 0; i < 10; ++i) out[i] = l[i] - ls;
    }
}

// ---------------------------------------------------------------------------
extern "C" void kernel_launch(void* const* d_in, const int* in_sizes, int n_in,
                              void* d_out, int out_size, void* d_ws, size_t ws_size,
                              hipStream_t stream) {
    float* out = (float*)d_out;

    static const int exp_sizes[28] = {
        8192, 32768,
        2048, 64, 2048, 4096,
        2048, 64, 2048, 64, 6144, 64,
        8192, 128, 8192, 128, 16384, 128,
        192, 192,
        12288, 192, 12288, 12288,
        4096, 64, 640, 10
    };
    bool ok = (n_in == 28);
    if (ok) for (int i = 0; i < 28; ++i) if (in_sizes[i] != exp_sizes[i]) ok = false;
    if (!ok) { sentinel_kernel<<<1, 64, 0, stream>>>(out, -5.0f); return; }

    const size_t RSZ = (size_t)NN * 64 * 2;            // 33.55 MB per region
    const size_t BIG_OFF = 8192 + 90112;               // control (8KB) + bf16 weight arena
    if (ws_size < BIG_OFF + 4 * RSZ) {
        sentinel_kernel<<<1, 64, 0, stream>>>(out, -7.0f);
        return;
    }

    const float* x     = (const float*)d_in[0];
    const int*   ei    = (const int*)d_in[1];
    const float* np1w  = (const float*)d_in[2];
    const float* np1b  = (const float*)d_in[3];
    const float* np2w  = (const float*)d_in[4];
    const float* np3w  = (const float*)d_in[5];
    const float* c0m1b = (const float*)d_in[7];
    const float* c0m2b = (const float*)d_in[9];
    const float* c0m4b = (const float*)d_in[11];
    const float* cm1b  = (const float*)d_in[13];
    const float* cm2b  = (const float*)d_in[15];
    const float* cm4b  = (const float*)d_in[17];
    const float* bng   = (const float*)d_in[18];
    const float* bnb   = (const float*)d_in[19];
    const float* fe1w  = (const float*)d_in[20];
    const float* fe1b  = (const float*)d_in[21];
    const float* fe2w  = (const float*)d_in[22];
    const float* fe3w  = (const float*)d_in[23];
    const float* acw   = (const float*)d_in[24];
    const float* acb   = (const float*)d_in[25];
    const float* flw   = (const float*)d_in[26];
    const float* flb   = (const float*)d_in[27];

    char* ws = (char*)d_ws;
    float* small = (float*)ws;
    float* tt    = small;          // [4][128]: per-layer trace(64)|total(64)
    float* scl   = small + 512;
    float* shf   = small + 576;
    float* oaccp = small + 640;    // [4][64] extractor partials

    u16* arena = (u16*)(ws + 8192);          // bf16 conv weights, 43008 elements

    char* big = ws + BIG_OFF;
    u16* S0 = (u16*)(big + 0 * RSZ);
    u16* S1 = (u16*)(big + 1 * RSZ);
    u16* S2 = (u16*)(big + 2 * RSZ);
    u16* S3 = (u16*)(big + 3 * RSZ);
    float* Abuf = (float*)S2;                // fp32 staging, dead after finalize_u0

    // BN partial buffers live in S2 (o2 slot) — dead between bmm and next conv12.
    float* psum = (float*)S2;                          // 64*2048
    float* psq  = psum + 64 * 2048;                    // 64*2048
    float* ptr  = psq + 64 * 2048;                     // 64*512

    hipMemsetAsync(small, 0, 4096, stream);
    hipMemsetAsync(Abuf, 0, (size_t)NN * 32 * 4, stream);

    cvt_weights<<<168, 256, 0, stream>>>((const float*)d_in[6], (const float*)d_in[8],
                                         (const float*)d_in[10], (const float*)d_in[12],
                                         (const float*)d_in[14], (const float*)d_in[16], arena);
    scatter_edges<<<2048, 256, 0, stream>>>(x, ei, Abuf);
    finalize_u0<<<1024, 256, 0, stream>>>(Abuf, S0, tt + 64);        // total -> tt[0][64..]
    trace_raw_cm<<<32, 256, 0, stream>>>(S0, tt);                    // trace -> tt[0][0..31]

    u16* U[3]  = { S0, S1, S0 };
    u16* O1[3] = { S1, S0, S1 };
    u16* R[3]  = { S1, S0, S1 };

    const float *aff_s = nullptr, *aff_h = nullptr;

    for (int l = 0; l < 3; ++l) {
        int Cin = (l == 0) ? 32 : 64;
        const u16 *w1b, *w2b, *w4b;
        const float *b1, *b2, *b4;
        if (l == 0) {
            w1b = arena;            b1 = c0m1b;
            w2b = arena + 2048;     b2 = c0m2b;
            w4b = arena + 4096;     b4 = c0m4b;
        } else {
            int m = l - 1;
            w1b = arena + 10240 + m * 4096;  b1 = cm1b + m * 64;
            w2b = arena + 18432 + m * 4096;  b2 = cm2b + m * 64;
            w4b = arena + 26624 + m * 8192;  b4 = cm4b + m * 64;
        }
        if (Cin == 32)
            conv12_t<1><<<2048, 256, 0, stream>>>(U[l], aff_s, aff_h, w1b, b1, w2b, b2, O1[l], S2);
        else
            conv12_t<2><<<2048, 256, 0, stream>>>(U[l], aff_s, aff_h, w1b, b1, w2b, b2, O1[l], S2);
        bmm_mfma<<<dim3(16, 64), 256, 0, stream>>>(O1[l], S2, S3);
        if (Cin == 32)
            conv4_t<3><<<2048, 256, 0, stream>>>(S3, U[l], aff_s, aff_h, w4b, b4, R[l], psum, psq, ptr);
        else
            conv4_t<4><<<2048, 256, 0, stream>>>(S3, U[l], aff_s, aff_h, w4b, b4, R[l], psum, psq, ptr);
        bn_finalize<<<64, 256, 0, stream>>>(psum, psq, ptr, bng + l * 64, bnb + l * 64,
                                            scl, shf, tt + (l + 1) * 128);
        aff_s = scl; aff_h = shf;
    }
    extractor_par<<<4, 256, 0, stream>>>(tt, np1w, np1b, np2w, np3w,
                                         fe1w, fe1b, fe2w, fe3w, oaccp);
    head_par<<<1, 256, 0, stream>>>(oaccp, acw, acb, flw, flb, out);
}

// Round 14
// 471.242 us; speedup vs baseline: 1.3369x; 1.2203x over previous
//
#include <hip/hip_runtime.h>
#include <hip/hip_bf16.h>

// Problem dims (fixed)
#define Nn   512
#define NN   262144        // N*N positions
#define EDG  16384

typedef unsigned short u16;
typedef short v8s __attribute__((ext_vector_type(8)));   // 8 bf16 lanes (4 VGPR)
typedef float v4f __attribute__((ext_vector_type(4)));
typedef u16 u16x8 __attribute__((ext_vector_type(8)));

__device__ __forceinline__ float b2f(u16 u) {
    union { unsigned int i; float f; } v; v.i = ((unsigned int)u) << 16; return v.f;
}
__device__ __forceinline__ u16 f2b(float f) {
    union { float f; unsigned int i; } v; v.f = f;
    unsigned int r = (v.i + 0x7FFFu + ((v.i >> 16) & 1u)) >> 16;
    return (u16)r;
}

// ---------------------------------------------------------------------------
__global__ void sentinel_kernel(float* __restrict__ out, float val) {
    if (threadIdx.x < 10) out[threadIdx.x] = val;
}

// ---------------------------------------------------------------------------
// K0: convert the 6 conv weight tensors (fp32) into one bf16 arena.
__global__ void cvt_weights(const float* __restrict__ s0, const float* __restrict__ s1,
                            const float* __restrict__ s2, const float* __restrict__ s3,
                            const float* __restrict__ s4, const float* __restrict__ s5,
                            u16* __restrict__ dst) {
    int t = blockIdx.x * 256 + threadIdx.x;
    if (t >= 43008) return;
    float v;
    if      (t < 2048)  v = s0[t];
    else if (t < 4096)  v = s1[t - 2048];
    else if (t < 10240) v = s2[t - 4096];
    else if (t < 18432) v = s3[t - 10240];
    else if (t < 26624) v = s4[t - 18432];
    else                v = s5[t - 26624];
    dst[t] = f2b(v);
}

// ---------------------------------------------------------------------------
// K1: scatter edges into A (fp32, pos-major [p][32]); x is fp32 [512][16]
__global__ void scatter_edges(const float* __restrict__ x, const int* __restrict__ ei,
                              float* __restrict__ A) {
    int t = blockIdx.x * 256 + threadIdx.x;
    if (t >= EDG * 32) return;
    int e = t >> 5, c = t & 31;
    int s = ei[e], d = ei[EDG + e];
    float v = (c < 16) ? x[s * 16 + c] : x[d * 16 + (c - 16)];
    atomicAdd(A + ((size_t)s * Nn + d) * 32 + c, v);
}

// ---------------------------------------------------------------------------
// K2: A fp32 pos-major [p][32] -> u0 CHANNEL-MAJOR bf16 [32][NN]; totals into tt0[64..]
__global__ __launch_bounds__(256) void finalize_u0(const float* __restrict__ A,
                                                   u16* __restrict__ u0,
                                                   float* __restrict__ total) {
    __shared__ u16 L[32 * 258];
    __shared__ float red[4][32];
    int t = threadIdx.x;
    int p0 = blockIdx.x * 256;
    const float* Ar = A + (size_t)(p0 + t) * 32;
    float v[32];
#pragma unroll
    for (int c = 0; c < 32; ++c) v[c] = Ar[c];
#pragma unroll
    for (int c = 0; c < 32; ++c) L[c * 258 + t] = f2b(v[c]);
    int wv = t >> 6;
#pragma unroll
    for (int c = 0; c < 32; ++c) {
        float r = v[c];
        for (int off = 32; off > 0; off >>= 1) r += __shfl_down(r, off);
        if ((t & 63) == 0) red[wv][c] = r;
    }
    __syncthreads();
    if (t < 32) atomicAdd(total + t, red[0][t] + red[1][t] + red[2][t] + red[3][t]);
    int off = (t & 31) * 8, rb = t >> 5;
#pragma unroll
    for (int pass = 0; pass < 4; ++pass) {
        int c = pass * 8 + rb;
        u16x8 w = *(const u16x8*)(L + c * 258 + off);
        *(u16x8*)(u0 + (size_t)c * NN + p0 + off) = w;
    }
}

// ---------------------------------------------------------------------------
// K3: trace of channel-major activation; grid = C blocks.
__global__ void trace_raw_cm(const u16* __restrict__ ucm, float* __restrict__ trraw) {
    int c = blockIdx.x, t = threadIdx.x;
    const u16* base = ucm + (size_t)c * NN;
    float s = b2f(base[(size_t)(2 * t) * 513]) + b2f(base[(size_t)(2 * t + 1) * 513]);
    for (int off = 32; off > 0; off >>= 1) s += __shfl_down(s, off);
    __shared__ float r[4];
    if ((t & 63) == 0) r[t >> 6] = s;
    __syncthreads();
    if (t == 0) trraw[c] = r[0] + r[1] + r[2] + r[3];
}

// ---------------------------------------------------------------------------
// K5: merged conv1+conv2 (r9, proven). Block = 128 positions.
template<int NCH>
__global__ __launch_bounds__(256) void conv12_t(
    const u16* __restrict__ src,
    const float* __restrict__ sc, const float* __restrict__ sh,
    const u16* __restrict__ w1, const float* __restrict__ b1,
    const u16* __restrict__ w2, const float* __restrict__ b2,
    u16* __restrict__ dst1, u16* __restrict__ dst2)
{
    __shared__ u16 LS[8320];
    const int C = NCH * 32;
    const int t = threadIdx.x;
    const int P0 = blockIdx.x * 128;
    const int lane = t & 63, wave = t >> 6;
    const int l15 = lane & 15, quad = lane >> 4;
    const int pw = wave * 32;
    const int sr = t >> 4;
    const int so = (t & 15) * 8;

    u16x8 pf[NCH][2];
#pragma unroll
    for (int kc = 0; kc < NCH; ++kc)
#pragma unroll
        for (int ps = 0; ps < 2; ++ps)
            pf[kc][ps] = *(const u16x8*)(src + (size_t)(kc * 32 + ps * 16 + sr) * NN + P0 + so);

    v4f acc[2][4][2];
#pragma unroll
    for (int s = 0; s < 2; ++s)
#pragma unroll
        for (int mt = 0; mt < 4; ++mt)
#pragma unroll
            for (int nt = 0; nt < 2; ++nt) acc[s][mt][nt] = (v4f){0.f, 0.f, 0.f, 0.f};

    {
        u16* Ln = LS;
#pragma unroll
        for (int ps = 0; ps < 2; ++ps) {
            int c = ps * 16 + sr;
            u16x8 v = pf[0][ps];
            if (sc) {
                float s = sc[c], f = sh[c];
#pragma unroll
                for (int j = 0; j < 8; ++j) v[j] = f2b(b2f(v[j]) * s + f);
            }
            *(u16x8*)(Ln + c * 130 + so) = v;
        }
    }
    __syncthreads();
#pragma unroll
    for (int kc = 0; kc < NCH; ++kc) {
        if (kc + 1 < NCH) {
            u16* Ln = LS + ((kc + 1) & 1) * 4160;
#pragma unroll
            for (int ps = 0; ps < 2; ++ps) {
                int c = ps * 16 + sr;
                int cg = (kc + 1) * 32 + c;
                u16x8 v = pf[kc + 1][ps];
                if (sc) {
                    float s = sc[cg], f = sh[cg];
#pragma unroll
                    for (int j = 0; j < 8; ++j) v[j] = f2b(b2f(v[j]) * s + f);
                }
                *(u16x8*)(Ln + c * 130 + so) = v;
            }
        }
        v8s af1[4], af2[4];
#pragma unroll
        for (int mt = 0; mt < 4; ++mt) {
            af1[mt] = *(const v8s*)(w1 + (mt * 16 + l15) * C + kc * 32 + quad * 8);
            af2[mt] = *(const v8s*)(w2 + (mt * 16 + l15) * C + kc * 32 + quad * 8);
        }
        const u16* Lb = LS + (kc & 1) * 4160;
#pragma unroll
        for (int nt = 0; nt < 2; ++nt) {
            const int p = pw + nt * 16 + l15;
            v8s b;
#pragma unroll
            for (int j = 0; j < 8; ++j) b[j] = (short)Lb[(quad * 8 + j) * 130 + p];
#pragma unroll
            for (int mt = 0; mt < 4; ++mt) {
                acc[0][mt][nt] = __builtin_amdgcn_mfma_f32_16x16x32_bf16(af1[mt], b, acc[0][mt][nt], 0, 0, 0);
                acc[1][mt][nt] = __builtin_amdgcn_mfma_f32_16x16x32_bf16(af2[mt], b, acc[1][mt][nt], 0, 0, 0);
            }
        }
        if (kc + 1 < NCH) __syncthreads();
    }
#pragma unroll
    for (int s = 0; s < 2; ++s) {
        __syncthreads();
        const float* bb = s ? b2 : b1;
#pragma unroll
        for (int mt = 0; mt < 4; ++mt)
#pragma unroll
            for (int r = 0; r < 4; ++r) {
                const int h = mt * 16 + quad * 4 + r;
                const float bv = bb[h];
#pragma unroll
                for (int nt = 0; nt < 2; ++nt)
                    LS[h * 130 + pw + nt * 16 + l15] = f2b(acc[s][mt][nt][r] + bv);
            }
        __syncthreads();
        u16* dd = s ? dst2 : dst1;
#pragma unroll
        for (int ps = 0; ps < 4; ++ps) {
            int h = ps * 16 + sr;
            u16x8 v = *(const u16x8*)(LS + h * 130 + so);
            __builtin_nontemporal_store(v, (u16x8*)(dd + (size_t)h * NN + P0 + so));
        }
    }
}

// ---------------------------------------------------------------------------
// K6: m4 conv (r9, proven): per-block BN stat/trace partials, no atomics.
template<int NCH>
__global__ __launch_bounds__(256) void conv4_t(
    const u16* __restrict__ mult, const u16* __restrict__ u,
    const float* __restrict__ sc, const float* __restrict__ sh,
    const u16* __restrict__ w, const float* __restrict__ bias,
    u16* __restrict__ dst,
    float* __restrict__ psum, float* __restrict__ psq, float* __restrict__ ptr)
{
    __shared__ u16 LS[8320];
    __shared__ float R1[64][4], R2[64][4];
    const int K = NCH * 32;
    const int t = threadIdx.x;
    const int P0 = blockIdx.x * 128;
    const int lane = t & 63, wave = t >> 6;
    const int l15 = lane & 15, quad = lane >> 4;
    const int pw = wave * 32;
    const int sr = t >> 4;
    const int so = (t & 15) * 8;

    u16x8 pf[NCH][2];
#pragma unroll
    for (int kc = 0; kc < NCH; ++kc)
#pragma unroll
        for (int ps = 0; ps < 2; ++ps) {
            int cg = kc * 32 + ps * 16 + sr;
            const u16* gp = (cg < 64) ? (mult + (size_t)cg * NN + P0 + so)
                                      : (u + (size_t)(cg - 64) * NN + P0 + so);
            pf[kc][ps] = *(const u16x8*)gp;
        }

    v4f acc[4][2];
#pragma unroll
    for (int mt = 0; mt < 4; ++mt)
#pragma unroll
        for (int nt = 0; nt < 2; ++nt) acc[mt][nt] = (v4f){0.f, 0.f, 0.f, 0.f};

#pragma unroll
    for (int ps = 0; ps < 2; ++ps)
        *(u16x8*)(LS + (ps * 16 + sr) * 130 + so) = pf[0][ps];
    __syncthreads();
#pragma unroll
    for (int kc = 0; kc < NCH; ++kc) {
        if (kc + 1 < NCH) {
            u16* Ln = LS + ((kc + 1) & 1) * 4160;
#pragma unroll
            for (int ps = 0; ps < 2; ++ps) {
                int c = ps * 16 + sr;
                int cg = (kc + 1) * 32 + c;
                u16x8 v = pf[kc + 1][ps];
                if (cg >= 64 && sc) {
                    float s = sc[cg - 64], f = sh[cg - 64];
#pragma unroll
                    for (int j = 0; j < 8; ++j) v[j] = f2b(b2f(v[j]) * s + f);
                }
                *(u16x8*)(Ln + c * 130 + so) = v;
            }
        }
        v8s af[4];
#pragma unroll
        for (int mt = 0; mt < 4; ++mt)
            af[mt] = *(const v8s*)(w + (mt * 16 + l15) * K + kc * 32 + quad * 8);
        const u16* Lb = LS + (kc & 1) * 4160;
#pragma unroll
        for (int nt = 0; nt < 2; ++nt) {
            const int p = pw + nt * 16 + l15;
            v8s b;
#pragma unroll
            for (int j = 0; j < 8; ++j) b[j] = (short)Lb[(quad * 8 + j) * 130 + p];
#pragma unroll
            for (int mt = 0; mt < 4; ++mt)
                acc[mt][nt] = __builtin_amdgcn_mfma_f32_16x16x32_bf16(af[mt], b, acc[mt][nt], 0, 0, 0);
        }
        if (kc + 1 < NCH) __syncthreads();
    }
    __syncthreads();
#pragma unroll
    for (int mt = 0; mt < 4; ++mt)
#pragma unroll
        for (int r = 0; r < 4; ++r) {
            const int h = mt * 16 + quad * 4 + r;
            const float bv = bias[h];
#pragma unroll
            for (int nt = 0; nt < 2; ++nt)
                LS[h * 130 + pw + nt * 16 + l15] = f2b(acc[mt][nt][r] + bv);
        }
    __syncthreads();
    {
        int c = t >> 2, q = t & 3;
        const u16* row = LS + c * 130 + q * 32;
        float s = 0.f, s2 = 0.f;
#pragma unroll
        for (int i = 0; i < 32; ++i) { float v = b2f(row[i]); s += v; s2 += v * v; }
        R1[c][q] = s; R2[c][q] = s2;
    }
    __syncthreads();
    {
        int i = P0 >> 9, j0 = P0 & 511;
        int blk = blockIdx.x;
        if (t < 64) {
            psum[t * 2048 + blk] = R1[t][0] + R1[t][1] + R1[t][2] + R1[t][3];
            psq[t * 2048 + blk]  = R2[t][0] + R2[t][1] + R2[t][2] + R2[t][3];
            if (j0 <= i && i < j0 + 128) ptr[t * 512 + i] = b2f(LS[t * 130 + (i - j0)]);
        }
    }
#pragma unroll
    for (int ps = 0; ps < 4; ++ps) {
        int h = ps * 16 + sr;
        u16x8 v = *(const u16x8*)(LS + h * 130 + so);
        __builtin_nontemporal_store(v, (u16x8*)(dst + (size_t)h * NN + P0 + so));
    }
}

// ---------------------------------------------------------------------------
// K7 v4 (REVERT, proven 46 µs): batched per-channel GEMM. Wave tile 128i x 32j
// (waves partition j -> each LB element gathered by exactly one wave);
// LA+LB single-buffered with register-prefetch staging.
__global__ __launch_bounds__(256) void bmm_mfma(const u16* __restrict__ Aall,
                                                const u16* __restrict__ Ball,
                                                u16* __restrict__ Call) {
    __shared__ u16 LA[128 * 72];
    __shared__ u16 LB[64 * 130];
    const int h = blockIdx.y;
    const int tx = blockIdx.x & 3, ty = blockIdx.x >> 2;
    const int t = threadIdx.x;
    const int lane = t & 63, wave = t >> 6;
    const int l15 = lane & 15, quad = lane >> 4;
    const int jb = wave * 32;
    const u16* Ap = Aall + (size_t)h * NN + (size_t)ty * 128 * 512;
    const u16* Bp = Ball + (size_t)h * NN + tx * 128;

    const int srow = t >> 3;
    const int scol = (t & 7) * 8;
    const int bkr = t >> 4;
    const int bjg = (t & 15) * 8;

    v4f acc[8][2];
#pragma unroll
    for (int mt = 0; mt < 8; ++mt)
#pragma unroll
        for (int nt = 0; nt < 2; ++nt) acc[mt][nt] = (v4f){0.f, 0.f, 0.f, 0.f};

    v8s ra[4], rb[4];
#pragma unroll
    for (int i = 0; i < 4; ++i) {
        ra[i] = *(const v8s*)(Ap + (size_t)(i * 32 + srow) * 512 + scol);
        rb[i] = *(const v8s*)(Bp + (size_t)(i * 16 + bkr) * 512 + bjg);
    }

    for (int ck = 0; ck < 8; ++ck) {
#pragma unroll
        for (int i = 0; i < 4; ++i) {
            *(v8s*)(LA + (i * 32 + srow) * 72 + scol) = ra[i];
            *(v8s*)(LB + (i * 16 + bkr) * 130 + bjg) = rb[i];
        }
        __syncthreads();
        if (ck < 7) {
            const int k0 = (ck + 1) * 64;
#pragma unroll
            for (int i = 0; i < 4; ++i) {
                ra[i] = *(const v8s*)(Ap + (size_t)(i * 32 + srow) * 512 + k0 + scol);
                rb[i] = *(const v8s*)(Bp + (size_t)(k0 + i * 16 + bkr) * 512 + bjg);
            }
        }
#pragma unroll
        for (int kk = 0; kk < 2; ++kk) {
            v8s b[2];
#pragma unroll
            for (int nt = 0; nt < 2; ++nt) {
                const int j = jb + nt * 16 + l15;
#pragma unroll
                for (int jj = 0; jj < 8; ++jj)
                    b[nt][jj] = (short)LB[(kk * 32 + quad * 8 + jj) * 130 + j];
            }
#pragma unroll
            for (int mh = 0; mh < 2; ++mh) {
                v8s a[4];
#pragma unroll
                for (int m = 0; m < 4; ++m)
                    a[m] = *(const v8s*)(LA + ((mh * 4 + m) * 16 + l15) * 72 + kk * 32 + quad * 8);
#pragma unroll
                for (int m = 0; m < 4; ++m)
#pragma unroll
                    for (int nt = 0; nt < 2; ++nt)
                        acc[mh * 4 + m][nt] = __builtin_amdgcn_mfma_f32_16x16x32_bf16(a[m], b[nt], acc[mh * 4 + m][nt], 0, 0, 0);
            }
        }
        __syncthreads();
    }

    u16* Cp = Call + (size_t)h * NN;
#pragma unroll
    for (int mt = 0; mt < 8; ++mt)
#pragma unroll
        for (int r = 0; r < 4; ++r) {
            const int i = ty * 128 + mt * 16 + quad * 4 + r;
#pragma unroll
            for (int nt = 0; nt < 2; ++nt) {
                const int j = tx * 128 + jb + nt * 16 + l15;
                Cp[i * 512 + j] = f2b(acc[mt][nt][r]);
            }
        }
}

// ---------------------------------------------------------------------------
// K11: reduce per-block partials; BN scale/shift; normalized totals & trace.
__global__ __launch_bounds__(256) void bn_finalize(
    const float* __restrict__ psum, const float* __restrict__ psq,
    const float* __restrict__ ptr,
    const float* __restrict__ g, const float* __restrict__ b,
    float* __restrict__ scale, float* __restrict__ shift,
    float* __restrict__ ttl) {
    int c = blockIdx.x, t = threadIdx.x;
    float s = 0.f, q = 0.f, tr = 0.f;
    for (int k = t; k < 2048; k += 256) { s += psum[c * 2048 + k]; q += psq[c * 2048 + k]; }
    for (int k = t; k < 512; k += 256) tr += ptr[c * 512 + k];
    for (int off = 32; off > 0; off >>= 1) {
        s += __shfl_down(s, off); q += __shfl_down(q, off); tr += __shfl_down(tr, off);
    }
    __shared__ float r1[4], r2[4], r3[4];
    if ((t & 63) == 0) { r1[t >> 6] = s; r2[t >> 6] = q; r3[t >> 6] = tr; }
    __syncthreads();
    if (t == 0) {
        s = r1[0] + r1[1] + r1[2] + r1[3];
        q = r2[0] + r2[1] + r2[2] + r2[3];
        tr = r3[0] + r3[1] + r3[2] + r3[3];
        float mean = s * (1.f / 262144.f);
        float var = q * (1.f / 262144.f) - mean * mean;
        float sc = g[c] * rsqrtf(fmaxf(var, 0.f) + 1e-5f);
        float sh = b[c] - mean * sc;
        scale[c] = sc;
        shift[c] = sh;
        ttl[64 + c] = sc * s + 262144.f * sh;   // total
        ttl[c]      = sc * tr + 512.f * sh;     // trace
    }
}

// ---------------------------------------------------------------------------
// K12a: one extractor per block (4 blocks, 256 thr). thread=(h,q): q = c-quarter.
__global__ __launch_bounds__(256) void extractor_par(
    const float* __restrict__ tt,
    const float* __restrict__ np1w, const float* __restrict__ np1b,
    const float* __restrict__ np2w, const float* __restrict__ np3w,
    const float* __restrict__ fe1w, const float* __restrict__ fe1b,
    const float* __restrict__ fe2w, const float* __restrict__ fe3w,
    float* __restrict__ oacc_part) {
    __shared__ float red[64][4];
    __shared__ float xo[64];
    const int li = blockIdx.x;
    const int t = threadIdx.x;
    const int h = t >> 2, q = t & 3;
    const int C = (li == 0) ? 32 : 64;
    const float* w1 = (li == 0) ? np1w : fe1w + (li - 1) * 4096;
    const float* b1 = (li == 0) ? np1b : fe1b + (li - 1) * 64;
    const float* w2 = (li == 0) ? np2w : fe2w + (li - 1) * 4096;
    const float* w3 = (li == 0) ? np3w : fe3w + (li - 1) * 4096;
    const float* tr = tt + li * 128;
    const float* to = tr + 64;
    const int cpq = C >> 2;
    float p = 0.f;
    for (int i = 0; i < cpq; ++i) {
        int c = q * cpq + i;
        p += (tr[c] * (1.f / 512.f)) * w1[h * C + c]
           + ((to[c] - tr[c]) * (1.f / (512.f * 511.f))) * w2[h * C + c];
    }
    red[h][q] = p;
    __syncthreads();
    if (q == 0) xo[h] = b1[h] + red[h][0] + red[h][1] + red[h][2] + red[h][3];
    __syncthreads();
    float o = xo[h];
    float p3 = 0.f;
    for (int i = 0; i < 16; ++i) {
        int f = q * 16 + i;
        p3 += fmaxf(xo[f], 0.f) * w3[h * 64 + f];
    }
    __syncthreads();
    red[h][q] = p3;
    __syncthreads();
    if (q == 0) oacc_part[li * 64 + h] = o + red[h][0] + red[h][1] + red[h][2] + red[h][3];
}

// ---------------------------------------------------------------------------
// K12b: head, 256 threads, 4-way split per output.
__global__ __launch_bounds__(256) void head_par(
    const float* __restrict__ oacc_part,
    const float* __restrict__ acw, const float* __restrict__ acb,
    const float* __restrict__ flw, const float* __restrict__ flb,
    float* __restrict__ out) {
    __shared__ float x[64], x2[64], red[64][4], l[10];
    const int t = threadIdx.x;
    const int h = t >> 2, q = t & 3;
    if (q == 0) {
        float oa = oacc_part[h] + oacc_part[64 + h] + oacc_part[128 + h] + oacc_part[192 + h];
        x[h] = fmaxf(oa, 0.f) * (1.f / 3.f);
    }
    __syncthreads();
    float p = 0.f;
    for (int i = 0; i < 16; ++i) { int f = q * 16 + i; p += x[f] * acw[h * 64 + f]; }
    red[h][q] = p;
    __syncthreads();
    if (q == 0) {
        float y = acb[h] + red[h][0] + red[h][1] + red[h][2] + red[h][3];
        x2[h] = x[h] + fmaxf(y, 0.f);
    }
    __syncthreads();
    if (t < 40) {
        int hh = t >> 2, qq = t & 3;
        float p2 = 0.f;
        for (int i = 0; i < 16; ++i) { int f = qq * 16 + i; p2 += x2[f] * flw[hh * 64 + f]; }
        red[hh][qq] = p2;
    }
    __syncthreads();
    if (t < 10) l[t] = flb[t] + red[t][0] + red[t][1] + red[t][2] + red[t][3];
    __syncthreads();
    if (t == 0) {
        float m = l[0];
        for (int i = 1; i < 10; ++i) m = fmaxf(m, l[i]);
        float se = 0.f;
        for (int i = 0; i < 10; ++i) se += expf(l[i] - m);
        float ls = m + logf(se);
        for (int i = 0; i < 10; ++i) out[i] = l[i] - ls;
    }
}

// ---------------------------------------------------------------------------
extern "C" void kernel_launch(void* const* d_in, const int* in_sizes, int n_in,
                              void* d_out, int out_size, void* d_ws, size_t ws_size,
                              hipStream_t stream) {
    float* out = (float*)d_out;

    static const int exp_sizes[28] = {
        8192, 32768,
        2048, 64, 2048, 4096,
        2048, 64, 2048, 64, 6144, 64,
        8192, 128, 8192, 128, 16384, 128,
        192, 192,
        12288, 192, 12288, 12288,
        4096, 64, 640, 10
    };
    bool ok = (n_in == 28);
    if (ok) for (int i = 0; i < 28; ++i) if (in_sizes[i] != exp_sizes[i]) ok = false;
    if (!ok) { sentinel_kernel<<<1, 64, 0, stream>>>(out, -5.0f); return; }

    const size_t RSZ = (size_t)NN * 64 * 2;            // 33.55 MB per region
    const size_t BIG_OFF = 8192 + 90112;               // control (8KB) + bf16 weight arena
    if (ws_size < BIG_OFF + 4 * RSZ) {
        sentinel_kernel<<<1, 64, 0, stream>>>(out, -7.0f);
        return;
    }

    const float* x     = (const float*)d_in[0];
    const int*   ei    = (const int*)d_in[1];
    const float* np1w  = (const float*)d_in[2];
    const float* np1b  = (const float*)d_in[3];
    const float* np2w  = (const float*)d_in[4];
    const float* np3w  = (const float*)d_in[5];
    const float* c0m1b = (const float*)d_in[7];
    const float* c0m2b = (const float*)d_in[9];
    const float* c0m4b = (const float*)d_in[11];
    const float* cm1b  = (const float*)d_in[13];
    const float* cm2b  = (const float*)d_in[15];
    const float* cm4b  = (const float*)d_in[17];
    const float* bng   = (const float*)d_in[18];
    const float* bnb   = (const float*)d_in[19];
    const float* fe1w  = (const float*)d_in[20];
    const float* fe1b  = (const float*)d_in[21];
    const float* fe2w  = (const float*)d_in[22];
    const float* fe3w  = (const float*)d_in[23];
    const float* acw   = (const float*)d_in[24];
    const float* acb   = (const float*)d_in[25];
    const float* flw   = (const float*)d_in[26];
    const float* flb   = (const float*)d_in[27];

    char* ws = (char*)d_ws;
    float* small = (float*)ws;
    float* tt    = small;          // [4][128]: per-layer trace(64)|total(64)
    float* scl   = small + 512;
    float* shf   = small + 576;
    float* oaccp = small + 640;    // [4][64] extractor partials

    u16* arena = (u16*)(ws + 8192);          // bf16 conv weights, 43008 elements

    char* big = ws + BIG_OFF;
    u16* S0 = (u16*)(big + 0 * RSZ);
    u16* S1 = (u16*)(big + 1 * RSZ);
    u16* S2 = (u16*)(big + 2 * RSZ);
    u16* S3 = (u16*)(big + 3 * RSZ);
    float* Abuf = (float*)S2;                // fp32 staging, dead after finalize_u0

    // BN partial buffers live in S2 (o2 slot) — dead between bmm and next conv12.
    float* psum = (float*)S2;                          // 64*2048
    float* psq  = psum + 64 * 2048;                    // 64*2048
    float* ptr  = psq + 64 * 2048;                     // 64*512

    hipMemsetAsync(small, 0, 4096, stream);
    hipMemsetAsync(Abuf, 0, (size_t)NN * 32 * 4, stream);

    cvt_weights<<<168, 256, 0, stream>>>((const float*)d_in[6], (const float*)d_in[8],
                                         (const float*)d_in[10], (const float*)d_in[12],
                                         (const float*)d_in[14], (const float*)d_in[16], arena);
    scatter_edges<<<2048, 256, 0, stream>>>(x, ei, Abuf);
    finalize_u0<<<1024, 256, 0, stream>>>(Abuf, S0, tt + 64);        // total -> tt[0][64..]
    trace_raw_cm<<<32, 256, 0, stream>>>(S0, tt);                    // trace -> tt[0][0..31]

    u16* U[3]  = { S0, S1, S0 };
    u16* O1[3] = { S1, S0, S1 };
    u16* R[3]  = { S1, S0, S1 };

    const float *aff_s = nullptr, *aff_h = nullptr;

    for (int l = 0; l < 3; ++l) {
        int Cin = (l == 0) ? 32 : 64;
        const u16 *w1b, *w2b, *w4b;
        const float *b1, *b2, *b4;
        if (l == 0) {
            w1b = arena;            b1 = c0m1b;
            w2b = arena + 2048;     b2 = c0m2b;
            w4b = arena + 4096;     b4 = c0m4b;
        } else {
            int m = l - 1;
            w1b = arena + 10240 + m * 4096;  b1 = cm1b + m * 64;
            w2b = arena + 18432 + m * 4096;  b2 = cm2b + m * 64;
            w4b = arena + 26624 + m * 8192;  b4 = cm4b + m * 64;
        }
        if (Cin == 32)
            conv12_t<1><<<2048, 256, 0, stream>>>(U[l], aff_s, aff_h, w1b, b1, w2b, b2, O1[l], S2);
        else
            conv12_t<2><<<2048, 256, 0, stream>>>(U[l], aff_s, aff_h, w1b, b1, w2b, b2, O1[l], S2);
        bmm_mfma<<<dim3(16, 64), 256, 0, stream>>>(O1[l], S2, S3);
        if (Cin == 32)
            conv4_t<3><<<2048, 256, 0, stream>>>(S3, U[l], aff_s, aff_h, w4b, b4, R[l], psum, psq, ptr);
        else
            conv4_t<4><<<2048, 256, 0, stream>>>(S3, U[l], aff_s, aff_h, w4b, b4, R[l], psum, psq, ptr);
        bn_finalize<<<64, 256, 0, stream>>>(psum, psq, ptr, bng + l * 64, bnb + l * 64,
                                            scl, shf, tt + (l + 1) * 128);
        aff_s = scl; aff_h = shf;
    }
    extractor_par<<<4, 256, 0, stream>>>(tt, np1w, np1b, np2w, np3w,
                                         fe1w, fe1b, fe2w, fe3w, oaccp);
    head_par<<<1, 256, 0, stream>>>(oaccp, acw, acb, flw, flb, out);
}